// Round 4
// baseline (228.944 us; speedup 1.0000x reference)
//
#include <hip/hip_runtime.h>
#include <stdint.h>

#define BB    2048
#define DIN   4096
#define DOUT  4096
#define NW    64      // 64-bit words per DIN bits

// ---------------------------------------------------------------------------
// ws layout:
//   xp  : [NW][BB]   u64   offset 0        (1 MB)   bits of x rows
//   mp  : [NW][DOUT] u64   offset 1 MB     (2 MB)   bits of mask columns
//
// Output is int32 0/1 (harness materializes the bool reference as int32).
// Mask dtype (u8-bool vs int32) detected inline in pack_m via wave reduction.
//
// R3 lesson: register-array prefetch in bgemm spilled to scratch
// (WRITE_SIZE 32->77 MB). R4: async global->LDS (global_load_lds, 16B) with
// double-buffered LDS — zero VGPR transit, loads overlap the compute phase.
// ---------------------------------------------------------------------------

__device__ __forceinline__ void async_load16(const void* g, void* l) {
    __builtin_amdgcn_global_load_lds(
        (const __attribute__((address_space(1))) unsigned int*)g,
        (__attribute__((address_space(3))) unsigned int*)l,
        16, 0, 0);
}

// Pack x (2048 x 4096 int32 of {0,1}) into xp[w][b]. One block per row;
// each wave ballots 64 coalesced elements into one u64 word.
__global__ void pack_x(const int* __restrict__ x,
                       unsigned long long* __restrict__ xp) {
    const int b    = blockIdx.x;
    const int tid  = threadIdx.x;
    const int wv   = tid >> 6;     // wave in block, 0..3
    const int lane = tid & 63;
    const int* row = x + (size_t)b * DIN;
    #pragma unroll
    for (int j = 0; j < 16; ++j) {
        int v = row[j * 256 + tid];
        unsigned long long word = __ballot(v != 0);
        if (lane == 0) xp[(size_t)(j * 4 + wv) * BB + b] = word;
    }
}

// Pack mask columns into mp[w][o]. Block = (w, o-tile of 1024); each thread
// builds 4 adjacent columns' words from 64 coalesced row reads.
__global__ void pack_m(const void* __restrict__ mraw,
                       unsigned long long* __restrict__ mp) {
    const int w   = blockIdx.x;              // 0..63
    const int o0  = blockIdx.y * 1024;
    const int tid = threadIdx.x;
    const int o   = o0 + tid * 4;

    // inline dtype detect: 4 bytes/thread from the first 1 KB, wave-reduce.
    const unsigned char* mb = (const unsigned char*)mraw;
    int myv = (mb[tid] != 0) + (mb[tid + 256] != 0) +
              (mb[tid + 512] != 0) + (mb[tid + 768] != 0);
    #pragma unroll
    for (int d = 32; d; d >>= 1) myv += __shfl_xor(myv, d);
    const bool isU8 = (myv > 64);   // u8-bool ~128, int32 ~32 per wave

    unsigned long long w0 = 0, w1 = 0, w2 = 0, w3 = 0;
    if (isU8) {
        const unsigned int* m8 = (const unsigned int*)mraw;  // 4 bool bytes
        #pragma unroll
        for (int k = 0; k < 64; ++k) {
            unsigned int v = m8[(size_t)(w * 64 + k) * (DOUT / 4) + (o >> 2)];
            unsigned long long bit = 1ull << k;
            if (v & 0x000000ffu) w0 |= bit;
            if (v & 0x0000ff00u) w1 |= bit;
            if (v & 0x00ff0000u) w2 |= bit;
            if (v & 0xff000000u) w3 |= bit;
        }
    } else {
        const int4* m32 = (const int4*)mraw;
        #pragma unroll
        for (int k = 0; k < 64; ++k) {
            int4 v = m32[(size_t)(w * 64 + k) * (DOUT / 4) + (o >> 2)];
            unsigned long long bit = 1ull << k;
            if (v.x) w0 |= bit;
            if (v.y) w1 |= bit;
            if (v.z) w2 |= bit;
            if (v.w) w3 |= bit;
        }
    }
    unsigned long long* dst = mp + (size_t)w * DOUT + o;
    dst[0] = w0; dst[1] = w1; dst[2] = w2; dst[3] = w3;
}

// Bit-GEMM: 128x128 tile per block, 256 threads, 8x8 register tile each.
// K staged in 16-word chunks, double-buffered LDS, async global->LDS loads
// for chunk k+1 issued before computing chunk k (one barrier per chunk).
__global__ __launch_bounds__(256, 2)
void bgemm(const unsigned long long* __restrict__ xp,
           const unsigned long long* __restrict__ mp,
           const int* __restrict__ thr,
           int* __restrict__ out) {
    const int o0   = blockIdx.x * 128;
    const int b0   = blockIdx.y * 128;
    const int tid  = threadIdx.x;
    const int tx   = tid & 15;   // o dimension
    const int ty   = tid >> 4;   // b dimension
    const int wv   = tid >> 6;   // wave in block, 0..3
    const int lane = tid & 63;

    __shared__ unsigned long long ldsx[2][16 * 128];
    __shared__ unsigned long long ldsm[2][16 * 128];

    // stage chunk -> LDS buffer buf via async direct-to-LDS 16B loads.
    // wave wv handles word-rows w = q*4+wv; lane writes lds byte offset
    // w*1024 + lane*16 (wave-uniform base + lane*16, as HW requires).
    auto stage = [&](int chunk, int buf) {
        const int wbase = chunk * 16;
        #pragma unroll
        for (int q = 0; q < 4; ++q) {
            const int w = q * 4 + wv;
            async_load16(xp + (size_t)(wbase + w) * BB + b0 + lane * 2,
                         &ldsx[buf][w * 128 + lane * 2]);
            async_load16(mp + (size_t)(wbase + w) * DOUT + o0 + lane * 2,
                         &ldsm[buf][w * 128 + lane * 2]);
        }
    };

    unsigned int acc[8][8];
    #pragma unroll
    for (int i = 0; i < 8; ++i)
        #pragma unroll
        for (int j = 0; j < 8; ++j) acc[i][j] = 0;

    stage(0, 0);
    __syncthreads();   // vmcnt drain: buf0 ready

    for (int chunk = 0; chunk < 4; ++chunk) {
        const int buf = chunk & 1;
        if (chunk < 3) stage(chunk + 1, buf ^ 1);   // overlaps compute below

        const unsigned long long* lx = ldsx[buf];
        const unsigned long long* lm = ldsm[buf];
        #pragma unroll 4
        for (int w = 0; w < 16; ++w) {
            // 16 u32 halves of the 8 x-words / 8 m-words this thread needs
            unsigned int xs[16], ms[16];
            #pragma unroll
            for (int r = 0; r < 4; ++r) {
                uint4 t = *(const uint4*)(lx + w * 128 + ty * 2 + r * 32);
                xs[4 * r] = t.x; xs[4 * r + 1] = t.y;
                xs[4 * r + 2] = t.z; xs[4 * r + 3] = t.w;
                uint4 u = *(const uint4*)(lm + w * 128 + tx * 2 + r * 32);
                ms[4 * r] = u.x; ms[4 * r + 1] = u.y;
                ms[4 * r + 2] = u.z; ms[4 * r + 3] = u.w;
            }
            #pragma unroll
            for (int i = 0; i < 8; ++i)
                #pragma unroll
                for (int j = 0; j < 8; ++j) {
                    // 2 v_xor + 2 v_bcnt (add folded into bcnt's S1 operand)
                    acc[i][j] = __popc(xs[2 * i + 1] ^ ms[2 * j + 1]) +
                                (__popc(xs[2 * i] ^ ms[2 * j]) + acc[i][j]);
                }
        }
        __syncthreads();   // drains chunk+1 loads; releases buf for reuse
    }

    // epilogue: sums = 4096 - X; out = (sums > thr) = (X < 4096 - thr)
    // write int32 0/1 (reference bool -> int32 in the harness)
    int limj[8];
    #pragma unroll
    for (int j = 0; j < 8; ++j)
        limj[j] = DIN - thr[o0 + tx * 2 + (j >> 1) * 32 + (j & 1)];

    #pragma unroll
    for (int i = 0; i < 8; ++i) {
        int b = b0 + ty * 2 + (i >> 1) * 32 + (i & 1);
        int* orow = out + (size_t)b * DOUT + o0;
        #pragma unroll
        for (int j2 = 0; j2 < 4; ++j2) {
            int2 v;
            v.x = ((int)acc[i][2 * j2]     < limj[2 * j2])     ? 1 : 0;
            v.y = ((int)acc[i][2 * j2 + 1] < limj[2 * j2 + 1]) ? 1 : 0;
            *(int2*)(orow + tx * 2 + j2 * 32) = v;
        }
    }
}

extern "C" void kernel_launch(void* const* d_in, const int* in_sizes, int n_in,
                              void* d_out, int out_size, void* d_ws, size_t ws_size,
                              hipStream_t stream) {
    const int* x          = (const int*)d_in[0];
    const void* masks     = d_in[1];           // bool: u8 or int32 (detected inline)
    const int* thresholds = (const int*)d_in[2];
    int* out              = (int*)d_out;

    unsigned long long* xp = (unsigned long long*)d_ws;                          // 1 MB
    unsigned long long* mp = (unsigned long long*)((char*)d_ws + (1 << 20));     // 2 MB

    pack_x<<<BB, 256, 0, stream>>>(x, xp);
    pack_m<<<dim3(NW, 4), 256, 0, stream>>>(masks, mp);
    bgemm<<<dim3(DOUT / 128, BB / 128), 256, 0, stream>>>(xp, mp, thresholds, out);
}

// Round 5
// 228.552 us; speedup vs baseline: 1.0017x; 1.0017x over previous
//
#include <hip/hip_runtime.h>
#include <stdint.h>

#define BB    2048
#define DIN   4096
#define DOUT  4096
#define NW    64      // 64-bit words per DIN bits

// ---------------------------------------------------------------------------
// ws layout:
//   xp  : [NW][BB]   u64   offset 0        (1 MB)   bits of x rows
//   mp  : [NW][DOUT] u64   offset 1 MB     (2 MB)   bits of mask columns
//
// Output int32 0/1 (harness materializes the bool reference as int32).
//
// R3 lesson: register-array prefetch spilled (WRITE 32->77 MB).
// R4 lesson: unroll-4 + 2x16 u32 temp arrays spilled again (VGPR 128 + 11 MB
//   scratch RT); compiler self-caps at the 128-VGPR occupancy granule even
//   though LDS already limits us to 2 blocks/CU. Fix: unroll 2, single temp
//   set, no min-waves hint. Async global->LDS double-buffer stays.
// R2->R3 delta showed ~10us/dispatch gap overhead -> pack_x+pack_m fused.
// ---------------------------------------------------------------------------

__device__ __forceinline__ void async_load16(const void* g, void* l) {
    __builtin_amdgcn_global_load_lds(
        (const __attribute__((address_space(1))) unsigned int*)g,
        (__attribute__((address_space(3))) unsigned int*)l,
        16, 0, 0);
}

// Fused packing: blocks [0,2048) pack x rows; blocks [2048,2304) pack mask
// columns. Block-granular branch -> no wave divergence.
__global__ void pack_all(const int* __restrict__ x,
                         const void* __restrict__ mraw,
                         unsigned long long* __restrict__ xp,
                         unsigned long long* __restrict__ mp) {
    const int tid = threadIdx.x;
    if (blockIdx.x < BB) {
        // ---- pack x: one block per row; each wave ballots 64 elems/word.
        const int b    = blockIdx.x;
        const int wv   = tid >> 6;
        const int lane = tid & 63;
        const int* row = x + (size_t)b * DIN;
        #pragma unroll
        for (int j = 0; j < 16; ++j) {
            int v = row[j * 256 + tid];
            unsigned long long word = __ballot(v != 0);
            if (lane == 0) xp[(size_t)(j * 4 + wv) * BB + b] = word;
        }
    } else {
        // ---- pack m: block = (w, o-tile of 1024); 4 adjacent columns/thread.
        const int bw  = blockIdx.x - BB;
        const int w   = bw & 63;
        const int o0  = (bw >> 6) * 1024;
        const int o   = o0 + tid * 4;

        // inline dtype detect (u8-bool vs int32): wave-reduce 1 KB prefix.
        const unsigned char* mb = (const unsigned char*)mraw;
        int myv = (mb[tid] != 0) + (mb[tid + 256] != 0) +
                  (mb[tid + 512] != 0) + (mb[tid + 768] != 0);
        #pragma unroll
        for (int d = 32; d; d >>= 1) myv += __shfl_xor(myv, d);
        const bool isU8 = (myv > 64);   // u8 ~128/wave, int32 ~32/wave

        unsigned long long w0 = 0, w1 = 0, w2 = 0, w3 = 0;
        if (isU8) {
            const unsigned int* m8 = (const unsigned int*)mraw;  // 4 bools
            #pragma unroll
            for (int k = 0; k < 64; ++k) {
                unsigned int v = m8[(size_t)(w * 64 + k) * (DOUT / 4) + (o >> 2)];
                unsigned long long bit = 1ull << k;
                if (v & 0x000000ffu) w0 |= bit;
                if (v & 0x0000ff00u) w1 |= bit;
                if (v & 0x00ff0000u) w2 |= bit;
                if (v & 0xff000000u) w3 |= bit;
            }
        } else {
            const int4* m32 = (const int4*)mraw;
            #pragma unroll
            for (int k = 0; k < 64; ++k) {
                int4 v = m32[(size_t)(w * 64 + k) * (DOUT / 4) + (o >> 2)];
                unsigned long long bit = 1ull << k;
                if (v.x) w0 |= bit;
                if (v.y) w1 |= bit;
                if (v.z) w2 |= bit;
                if (v.w) w3 |= bit;
            }
        }
        unsigned long long* dst = mp + (size_t)w * DOUT + o;
        dst[0] = w0; dst[1] = w1; dst[2] = w2; dst[3] = w3;
    }
}

// Bit-GEMM: 128x128 tile per block, 256 threads, 8x8 register tile each.
// K staged in 16-word chunks, double-buffered LDS, async global->LDS loads
// for chunk k+1 issued before computing chunk k (one barrier per chunk).
__global__ __launch_bounds__(256)
void bgemm(const unsigned long long* __restrict__ xp,
           const unsigned long long* __restrict__ mp,
           const int* __restrict__ thr,
           int* __restrict__ out) {
    const int o0   = blockIdx.x * 128;
    const int b0   = blockIdx.y * 128;
    const int tid  = threadIdx.x;
    const int tx   = tid & 15;   // o dimension
    const int ty   = tid >> 4;   // b dimension
    const int wv   = tid >> 6;   // wave in block, 0..3
    const int lane = tid & 63;

    __shared__ unsigned long long ldsx[2][16 * 128];
    __shared__ unsigned long long ldsm[2][16 * 128];

    // async stage: wave wv -> word-rows w = q*4+wv; lane writes byte offset
    // w*1024 + lane*16 (wave-uniform base + lane*16, as the HW requires).
    auto stage = [&](int chunk, int buf) {
        const int wbase = chunk * 16;
        #pragma unroll
        for (int q = 0; q < 4; ++q) {
            const int w = q * 4 + wv;
            async_load16(xp + (size_t)(wbase + w) * BB + b0 + lane * 2,
                         &ldsx[buf][w * 128 + lane * 2]);
            async_load16(mp + (size_t)(wbase + w) * DOUT + o0 + lane * 2,
                         &ldsm[buf][w * 128 + lane * 2]);
        }
    };

    unsigned int acc[8][8];
    #pragma unroll
    for (int i = 0; i < 8; ++i)
        #pragma unroll
        for (int j = 0; j < 8; ++j) acc[i][j] = 0;

    stage(0, 0);
    __syncthreads();   // vmcnt drain: buf0 ready

    for (int chunk = 0; chunk < 4; ++chunk) {
        const int buf = chunk & 1;
        if (chunk < 3) stage(chunk + 1, buf ^ 1);   // overlaps compute below

        const unsigned long long* lx = ldsx[buf];
        const unsigned long long* lm = ldsm[buf];
        #pragma unroll 2
        for (int w = 0; w < 16; ++w) {
            // single temp set (32 VGPRs) -> no spill; lx read is a 16-lane
            // broadcast, lm read is 16 distinct 16B addrs x4 replication.
            uint4 xq[4], mq[4];
            #pragma unroll
            for (int r = 0; r < 4; ++r) {
                xq[r] = *(const uint4*)(lx + w * 128 + ty * 2 + r * 32);
                mq[r] = *(const uint4*)(lm + w * 128 + tx * 2 + r * 32);
            }
            const unsigned int* xs = (const unsigned int*)xq;
            const unsigned int* ms = (const unsigned int*)mq;
            #pragma unroll
            for (int i = 0; i < 8; ++i)
                #pragma unroll
                for (int j = 0; j < 8; ++j) {
                    // 2 v_xor + 2 v_bcnt (adds fold into bcnt's S1 operand)
                    acc[i][j] = __popc(xs[2 * i + 1] ^ ms[2 * j + 1]) +
                                (__popc(xs[2 * i] ^ ms[2 * j]) + acc[i][j]);
                }
        }
        __syncthreads();   // drains chunk+1 loads; releases buf for reuse
    }

    // epilogue: sums = 4096 - X; out = (sums > thr) = (X < 4096 - thr)
    int limj[8];
    #pragma unroll
    for (int j = 0; j < 8; ++j)
        limj[j] = DIN - thr[o0 + tx * 2 + (j >> 1) * 32 + (j & 1)];

    #pragma unroll
    for (int i = 0; i < 8; ++i) {
        int b = b0 + ty * 2 + (i >> 1) * 32 + (i & 1);
        int* orow = out + (size_t)b * DOUT + o0;
        #pragma unroll
        for (int j2 = 0; j2 < 4; ++j2) {
            int2 v;
            v.x = ((int)acc[i][2 * j2]     < limj[2 * j2])     ? 1 : 0;
            v.y = ((int)acc[i][2 * j2 + 1] < limj[2 * j2 + 1]) ? 1 : 0;
            *(int2*)(orow + tx * 2 + j2 * 32) = v;
        }
    }
}

extern "C" void kernel_launch(void* const* d_in, const int* in_sizes, int n_in,
                              void* d_out, int out_size, void* d_ws, size_t ws_size,
                              hipStream_t stream) {
    const int* x          = (const int*)d_in[0];
    const void* masks     = d_in[1];           // bool: u8 or int32 (detected inline)
    const int* thresholds = (const int*)d_in[2];
    int* out              = (int*)d_out;

    unsigned long long* xp = (unsigned long long*)d_ws;                          // 1 MB
    unsigned long long* mp = (unsigned long long*)((char*)d_ws + (1 << 20));     // 2 MB

    pack_all<<<BB + NW * 4, 256, 0, stream>>>(x, masks, xp, mp);
    bgemm<<<dim3(DOUT / 128, BB / 128), 256, 0, stream>>>(xp, mp, thresholds, out);
}

// Round 6
// 209.808 us; speedup vs baseline: 1.0912x; 1.0893x over previous
//
#include <hip/hip_runtime.h>
#include <stdint.h>

#define BB    2048
#define DIN   4096
#define DOUT  4096
#define NW    64      // 64-bit words per DIN bits

// ---------------------------------------------------------------------------
// ws layout:
//   xp  : [NW][BB]   u64   offset 0        (1 MB)   bits of x rows
//   mp  : [NW][DOUT] u64   offset 1 MB     (2 MB)   bits of mask columns
//
// Output int32 0/1 (harness materializes the bool reference as int32).
//
// R3: register-array prefetch spilled (WRITE 32->77 MB).
// R4: unroll-4 + 2x16 temps spilled (VGPR 128 + 11 MB scratch RT).
// R5: no spill (WRITE exactly 32.8 MB) but VALU issue = 69.7us vs 27.3us
//     floor -> compiler emits ~2.5x the minimal ops (no bcnt-fold, movs).
// R6: inner core in inline asm: exactly 2x v_xor_b32 + 2x v_bcnt_u32_b32
//     per u64 pair, acc chained through bcnt's S1 operand.
// Totals R2-R5 pinned at ~228 while kernels changed -> ~130us harness floor;
// controllable slice is pack (~15) + bgemm.
// ---------------------------------------------------------------------------

__device__ __forceinline__ void async_load16(const void* g, void* l) {
    __builtin_amdgcn_global_load_lds(
        (const __attribute__((address_space(1))) unsigned int*)g,
        (__attribute__((address_space(3))) unsigned int*)l,
        16, 0, 0);
}

// Fused packing: blocks [0,2048) pack x rows; blocks [2048,2304) pack mask
// columns. Block-granular branch -> no wave divergence.
__global__ void pack_all(const int* __restrict__ x,
                         const void* __restrict__ mraw,
                         unsigned long long* __restrict__ xp,
                         unsigned long long* __restrict__ mp) {
    const int tid = threadIdx.x;
    if (blockIdx.x < BB) {
        // ---- pack x: one block per row; each wave ballots 64 elems/word.
        const int b    = blockIdx.x;
        const int wv   = tid >> 6;
        const int lane = tid & 63;
        const int* row = x + (size_t)b * DIN;
        #pragma unroll
        for (int j = 0; j < 16; ++j) {
            int v = row[j * 256 + tid];
            unsigned long long word = __ballot(v != 0);
            if (lane == 0) xp[(size_t)(j * 4 + wv) * BB + b] = word;
        }
    } else {
        // ---- pack m: block = (w, o-tile of 1024); 4 adjacent columns/thread.
        const int bw  = blockIdx.x - BB;
        const int w   = bw & 63;
        const int o0  = (bw >> 6) * 1024;
        const int o   = o0 + tid * 4;

        // inline dtype detect (u8-bool vs int32): wave-reduce 1 KB prefix.
        const unsigned char* mb = (const unsigned char*)mraw;
        int myv = (mb[tid] != 0) + (mb[tid + 256] != 0) +
                  (mb[tid + 512] != 0) + (mb[tid + 768] != 0);
        #pragma unroll
        for (int d = 32; d; d >>= 1) myv += __shfl_xor(myv, d);
        const bool isU8 = (myv > 64);   // u8 ~128/wave, int32 ~32/wave

        unsigned long long w0 = 0, w1 = 0, w2 = 0, w3 = 0;
        if (isU8) {
            const unsigned int* m8 = (const unsigned int*)mraw;  // 4 bools
            #pragma unroll
            for (int k = 0; k < 64; ++k) {
                unsigned int v = m8[(size_t)(w * 64 + k) * (DOUT / 4) + (o >> 2)];
                unsigned long long bit = 1ull << k;
                if (v & 0x000000ffu) w0 |= bit;
                if (v & 0x0000ff00u) w1 |= bit;
                if (v & 0x00ff0000u) w2 |= bit;
                if (v & 0xff000000u) w3 |= bit;
            }
        } else {
            const int4* m32 = (const int4*)mraw;
            #pragma unroll
            for (int k = 0; k < 64; ++k) {
                int4 v = m32[(size_t)(w * 64 + k) * (DOUT / 4) + (o >> 2)];
                unsigned long long bit = 1ull << k;
                if (v.x) w0 |= bit;
                if (v.y) w1 |= bit;
                if (v.z) w2 |= bit;
                if (v.w) w3 |= bit;
            }
        }
        unsigned long long* dst = mp + (size_t)w * DOUT + o;
        dst[0] = w0; dst[1] = w1; dst[2] = w2; dst[3] = w3;
    }
}

// exactly 4 VALU ops per u64-pair: t=xlo^mlo; acc=bcnt(t)+acc;
// t=xhi^mhi; acc=bcnt(t)+acc.  Non-volatile, register-only -> the
// scheduler can interleave independent pairs.
__device__ __forceinline__ void xnor_acc(unsigned int xlo, unsigned int xhi,
                                         unsigned int mlo, unsigned int mhi,
                                         unsigned int& acc) {
    unsigned int t;
    asm("v_xor_b32 %0, %2, %3\n\t"
        "v_bcnt_u32_b32 %1, %0, %1\n\t"
        "v_xor_b32 %0, %4, %5\n\t"
        "v_bcnt_u32_b32 %1, %0, %1"
        : "=&v"(t), "+v"(acc)
        : "v"(xlo), "v"(mlo), "v"(xhi), "v"(mhi));
}

// Bit-GEMM: 128x128 tile per block, 256 threads, 8x8 register tile each.
// K staged in 16-word chunks, double-buffered LDS, async global->LDS loads
// for chunk k+1 issued before computing chunk k (one barrier per chunk).
__global__ __launch_bounds__(256)
void bgemm(const unsigned long long* __restrict__ xp,
           const unsigned long long* __restrict__ mp,
           const int* __restrict__ thr,
           int* __restrict__ out) {
    const int o0   = blockIdx.x * 128;
    const int b0   = blockIdx.y * 128;
    const int tid  = threadIdx.x;
    const int tx   = tid & 15;   // o dimension
    const int ty   = tid >> 4;   // b dimension
    const int wv   = tid >> 6;   // wave in block, 0..3
    const int lane = tid & 63;

    __shared__ unsigned long long ldsx[2][16 * 128];
    __shared__ unsigned long long ldsm[2][16 * 128];

    // async stage: wave wv -> word-rows w = q*4+wv; lane writes byte offset
    // w*1024 + lane*16 (wave-uniform base + lane*16, as the HW requires).
    auto stage = [&](int chunk, int buf) {
        const int wbase = chunk * 16;
        #pragma unroll
        for (int q = 0; q < 4; ++q) {
            const int w = q * 4 + wv;
            async_load16(xp + (size_t)(wbase + w) * BB + b0 + lane * 2,
                         &ldsx[buf][w * 128 + lane * 2]);
            async_load16(mp + (size_t)(wbase + w) * DOUT + o0 + lane * 2,
                         &ldsm[buf][w * 128 + lane * 2]);
        }
    };

    unsigned int acc[8][8];
    #pragma unroll
    for (int i = 0; i < 8; ++i)
        #pragma unroll
        for (int j = 0; j < 8; ++j) acc[i][j] = 0;

    stage(0, 0);
    __syncthreads();   // vmcnt drain: buf0 ready

    for (int chunk = 0; chunk < 4; ++chunk) {
        const int buf = chunk & 1;
        if (chunk < 3) stage(chunk + 1, buf ^ 1);   // overlaps compute below

        const unsigned long long* lx = ldsx[buf];
        const unsigned long long* lm = ldsm[buf];
        #pragma unroll 2
        for (int w = 0; w < 16; ++w) {
            // single temp set (32 VGPRs) -> no spill; lx read is a 16-lane
            // broadcast (free), lm read is 16 distinct 16B addrs.
            uint4 xq[4], mq[4];
            #pragma unroll
            for (int r = 0; r < 4; ++r) {
                xq[r] = *(const uint4*)(lx + w * 128 + ty * 2 + r * 32);
                mq[r] = *(const uint4*)(lm + w * 128 + tx * 2 + r * 32);
            }
            const unsigned int* xs = (const unsigned int*)xq;
            const unsigned int* ms = (const unsigned int*)mq;
            #pragma unroll
            for (int i = 0; i < 8; ++i)
                #pragma unroll
                for (int j = 0; j < 8; ++j)
                    xnor_acc(xs[2 * i], xs[2 * i + 1],
                             ms[2 * j], ms[2 * j + 1], acc[i][j]);
        }
        __syncthreads();   // drains chunk+1 loads; releases buf for reuse
    }

    // epilogue: sums = 4096 - X; out = (sums > thr) = (X < 4096 - thr)
    int limj[8];
    #pragma unroll
    for (int j = 0; j < 8; ++j)
        limj[j] = DIN - thr[o0 + tx * 2 + (j >> 1) * 32 + (j & 1)];

    #pragma unroll
    for (int i = 0; i < 8; ++i) {
        int b = b0 + ty * 2 + (i >> 1) * 32 + (i & 1);
        int* orow = out + (size_t)b * DOUT + o0;
        #pragma unroll
        for (int j2 = 0; j2 < 4; ++j2) {
            int2 v;
            v.x = ((int)acc[i][2 * j2]     < limj[2 * j2])     ? 1 : 0;
            v.y = ((int)acc[i][2 * j2 + 1] < limj[2 * j2 + 1]) ? 1 : 0;
            *(int2*)(orow + tx * 2 + j2 * 32) = v;
        }
    }
}

extern "C" void kernel_launch(void* const* d_in, const int* in_sizes, int n_in,
                              void* d_out, int out_size, void* d_ws, size_t ws_size,
                              hipStream_t stream) {
    const int* x          = (const int*)d_in[0];
    const void* masks     = d_in[1];           // bool: u8 or int32 (detected inline)
    const int* thresholds = (const int*)d_in[2];
    int* out              = (int*)d_out;

    unsigned long long* xp = (unsigned long long*)d_ws;                          // 1 MB
    unsigned long long* mp = (unsigned long long*)((char*)d_ws + (1 << 20));     // 2 MB

    pack_all<<<BB + NW * 4, 256, 0, stream>>>(x, masks, xp, mp);
    bgemm<<<dim3(DOUT / 128, BB / 128), 256, 0, stream>>>(xp, mp, thresholds, out);
}

// Round 7
// 188.766 us; speedup vs baseline: 1.2128x; 1.1115x over previous
//
#include <hip/hip_runtime.h>
#include <stdint.h>

#define BB    2048
#define DIN   4096
#define DOUT  4096

// ---------------------------------------------------------------------------
// R7: i8 MFMA reformulation. x,m -> ±1 int8; dot± = 2*sums - 4096;
//     out = sums > thr  <=>  dot± > 2*thr - 4096.  Exact in i32.
// ws layout:
//   x8  : int8 ±1 [BB][DIN]        offset 0      (8 MB)
//   m8T : int8 ±1 [DOUT][DIN]      offset 8 MB  (16 MB)   transposed masks
// Output int32 0/1.
// bitwise-VALU approach plateaued at 72us (issue 2x the 4-op floor even in
// asm); i8 MFMA pipe = 4404 TOPS -> 15.6us compute floor, ~21us LDS-bound.
// ---------------------------------------------------------------------------

using v4i  = __attribute__((ext_vector_type(4)))  int;
using v16i = __attribute__((ext_vector_type(16))) int;

__device__ __forceinline__ void async_load16(const void* g, void* l) {
    __builtin_amdgcn_global_load_lds(
        (const __attribute__((address_space(1))) unsigned int*)g,
        (__attribute__((address_space(3))) unsigned int*)l,
        16, 0, 0);
}

// bytes {0,1} -> {+1, -1(0xFF)}; no cross-byte carries.
__device__ __forceinline__ unsigned int to_pm1(unsigned int c) {
    return c + ((c ^ 0x01010101u) * 255u);
}

// Fused packing.
// blocks [0,BB): x int32 {0,1} row -> x8 ±1 bytes (same layout).
// blocks [BB, BB+4096): 64x64 transpose tile of masks -> m8T ±1 bytes.
__global__ void pack_all(const int* __restrict__ x,
                         const void* __restrict__ mraw,
                         char* __restrict__ x8,
                         char* __restrict__ m8T) {
    const int tid = threadIdx.x;
    if (blockIdx.x < BB) {
        const int row = blockIdx.x;
        const int4* src = (const int4*)(x + (size_t)row * DIN);
        unsigned int* dst = (unsigned int*)(x8 + (size_t)row * DIN);
        #pragma unroll
        for (int q = 0; q < 4; ++q) {
            int4 v = src[q * 256 + tid];           // coalesced 16B/lane
            unsigned int t = (unsigned int)(v.x & 1) |
                             ((unsigned int)(v.y & 1) << 8) |
                             ((unsigned int)(v.z & 1) << 16) |
                             ((unsigned int)(v.w & 1) << 24);
            dst[q * 256 + tid] = to_pm1(t);        // coalesced 4B/lane
        }
    } else {
        const int bw = blockIdx.x - BB;            // 0..4095
        const int k0 = (bw & 63) * 64;
        const int n0 = (bw >> 6) * 64;

        // inline dtype detect (u8-bool vs int32): wave-reduce 1 KB prefix.
        const unsigned char* mb = (const unsigned char*)mraw;
        int myv = (mb[tid] != 0) + (mb[tid + 256] != 0) +
                  (mb[tid + 512] != 0) + (mb[tid + 768] != 0);
        #pragma unroll
        for (int d = 32; d; d >>= 1) myv += __shfl_xor(myv, d);
        const bool isU8 = (myv > 64);   // u8 ~128/wave, int32 ~32/wave

        // 4x4 byte micro-tile per thread: rows k0+k4..+3, cols n0+n4..+3
        const int n4 = (tid & 15) * 4;
        const int k4 = (tid >> 4) * 4;
        unsigned int a[4];
        if (isU8) {
            #pragma unroll
            for (int r = 0; r < 4; ++r)
                a[r] = *(const unsigned int*)(mb + (size_t)(k0 + k4 + r) * DOUT + n0 + n4);
        } else {
            const int4* m32 = (const int4*)mraw;
            #pragma unroll
            for (int r = 0; r < 4; ++r) {
                int4 v = m32[((size_t)(k0 + k4 + r) * DOUT + n0 + n4) >> 2];
                a[r] = (unsigned int)(v.x & 1) |
                       ((unsigned int)(v.y & 1) << 8) |
                       ((unsigned int)(v.z & 1) << 16) |
                       ((unsigned int)(v.w & 1) << 24);
            }
        }
        // 4x4 byte transpose via v_perm (sel 0-3 = src1/lo, 4-7 = src0/hi)
        unsigned int x0 = __builtin_amdgcn_perm(a[1], a[0], 0x05010400u);
        unsigned int x1 = __builtin_amdgcn_perm(a[3], a[2], 0x05010400u);
        unsigned int x2 = __builtin_amdgcn_perm(a[1], a[0], 0x07030602u);
        unsigned int x3 = __builtin_amdgcn_perm(a[3], a[2], 0x07030602u);
        unsigned int c0 = __builtin_amdgcn_perm(x1, x0, 0x05040100u);
        unsigned int c1 = __builtin_amdgcn_perm(x1, x0, 0x07060302u);
        unsigned int c2 = __builtin_amdgcn_perm(x3, x2, 0x05040100u);
        unsigned int c3 = __builtin_amdgcn_perm(x3, x2, 0x07060302u);
        // write column j -> m8T[n0+n4+j][k0+k4..+3], converted to ±1
        *(unsigned int*)(m8T + (size_t)(n0 + n4 + 0) * DIN + k0 + k4) = to_pm1(c0);
        *(unsigned int*)(m8T + (size_t)(n0 + n4 + 1) * DIN + k0 + k4) = to_pm1(c1);
        *(unsigned int*)(m8T + (size_t)(n0 + n4 + 2) * DIN + k0 + k4) = to_pm1(c2);
        *(unsigned int*)(m8T + (size_t)(n0 + n4 + 3) * DIN + k0 + k4) = to_pm1(c3);
    }
}

// i8 MFMA GEMM: 128(m)x128(n) block tile, 4 waves as 2x2 of 64x64 wave
// tiles, each wave tile = 2x2 of v_mfma_i32_32x32x32_i8. BK=64 chunks,
// double-buffered LDS, async global->LDS staging (R6 pattern).
// LDS k-groups XOR-swizzled (slot = kgroup ^ ((row>>1)&3)) so frag reads sit
// at the structural 4-way floor instead of 16-way.
__global__ __launch_bounds__(256)
void bgemm(const char* __restrict__ x8,
           const char* __restrict__ m8T,
           const int* __restrict__ thr,
           int* __restrict__ out) {
    const int o0   = blockIdx.x * 128;   // n
    const int b0   = blockIdx.y * 128;   // m
    const int tid  = threadIdx.x;
    const int lane = tid & 63;
    const int wv   = tid >> 6;
    const int wm   = (wv & 1) * 64;      // wave tile m origin
    const int wn   = (wv >> 1) * 64;     // wave tile n origin
    const int l31  = lane & 31;
    const int lh   = lane >> 5;
    const int rsw  = (lane >> 1) & 3;    // row swizzle term for frag reads

    __shared__ __align__(16) char lA[2][128 * 64];
    __shared__ __align__(16) char lB[2][128 * 64];

    // stage chunk c -> buf. 8 lds-load instrs per array (16 rows each);
    // wave wv covers rows wv*32 + h*16. lane l -> row r0+l/4, slot l&3,
    // fetching global k-group (l&3) ^ ((row>>1)&3)  [the swizzle].
    auto stage = [&](int c, int buf) {
        const int k0 = c * 64;
        #pragma unroll
        for (int h = 0; h < 2; ++h) {
            const int r0  = wv * 32 + h * 16;
            const int row = r0 + (lane >> 2);
            const int g   = (lane & 3) ^ ((row >> 1) & 3);
            async_load16(x8 + (size_t)(b0 + row) * DIN + k0 + g * 16,
                         &lA[buf][r0 * 64 + lane * 16]);
            async_load16(m8T + (size_t)(o0 + row) * DIN + k0 + g * 16,
                         &lB[buf][r0 * 64 + lane * 16]);
        }
    };

    v16i acc[2][2];
    #pragma unroll
    for (int t = 0; t < 2; ++t)
        #pragma unroll
        for (int u = 0; u < 2; ++u)
            acc[t][u] = (v16i)(0);

    stage(0, 0);
    __syncthreads();

    for (int c = 0; c < 64; ++c) {
        const int buf = c & 1;
        if (c < 63) stage(c + 1, buf ^ 1);   // async, overlaps compute

        #pragma unroll
        for (int ks = 0; ks < 2; ++ks) {
            const int slot = ((ks * 2 + lh) ^ rsw) * 16;   // byte offset of k-group
            v4i aF[2], bF[2];
            #pragma unroll
            for (int t = 0; t < 2; ++t) {
                aF[t] = *(const v4i*)&lA[buf][(wm + t * 32 + l31) * 64 + slot];
                bF[t] = *(const v4i*)&lB[buf][(wn + t * 32 + l31) * 64 + slot];
            }
            acc[0][0] = __builtin_amdgcn_mfma_i32_32x32x32_i8(aF[0], bF[0], acc[0][0], 0, 0, 0);
            acc[0][1] = __builtin_amdgcn_mfma_i32_32x32x32_i8(aF[0], bF[1], acc[0][1], 0, 0, 0);
            acc[1][0] = __builtin_amdgcn_mfma_i32_32x32x32_i8(aF[1], bF[0], acc[1][0], 0, 0, 0);
            acc[1][1] = __builtin_amdgcn_mfma_i32_32x32x32_i8(aF[1], bF[1], acc[1][1], 0, 0, 0);
        }
        __syncthreads();   // drains chunk+1 loads; releases buf
    }

    // epilogue: out = (dot± > 2*thr - 4096).
    // C/D layout (measured): col = lane&31 = n; row = (reg&3) + 8*(reg>>2) + 4*(lane>>5).
    #pragma unroll
    for (int u = 0; u < 2; ++u) {
        const int o   = o0 + wn + u * 32 + l31;
        const int lim = 2 * thr[o] - DIN;
        #pragma unroll
        for (int t = 0; t < 2; ++t) {
            #pragma unroll
            for (int r = 0; r < 16; ++r) {
                const int rowl = (r & 3) + 8 * (r >> 2) + 4 * lh;
                const int b    = b0 + wm + t * 32 + rowl;
                out[(size_t)b * DOUT + o] = (acc[t][u][r] > lim) ? 1 : 0;
            }
        }
    }
}

extern "C" void kernel_launch(void* const* d_in, const int* in_sizes, int n_in,
                              void* d_out, int out_size, void* d_ws, size_t ws_size,
                              hipStream_t stream) {
    const int* x          = (const int*)d_in[0];
    const void* masks     = d_in[1];           // bool: u8 or int32 (detected inline)
    const int* thresholds = (const int*)d_in[2];
    int* out              = (int*)d_out;

    char* x8  = (char*)d_ws;                          // 8 MB
    char* m8T = (char*)d_ws + ((size_t)8 << 20);      // 16 MB

    pack_all<<<BB + 4096, 256, 0, stream>>>(x, masks, x8, m8T);
    bgemm<<<dim3(DOUT / 128, BB / 128), 256, 0, stream>>>(x8, m8T, thresholds, out);
}

// Round 8
// 176.851 us; speedup vs baseline: 1.2946x; 1.0674x over previous
//
#include <hip/hip_runtime.h>
#include <stdint.h>

#define BB    2048
#define DIN   4096
#define DOUT  4096

// ---------------------------------------------------------------------------
// i8 MFMA bit-GEMM. x,m -> ±1 int8; dot± = 2*sums - 4096;
// out = sums > thr  <=>  dot± > 2*thr - 4096. Exact in i32. (R7: absmax 0)
// ws: x8 ±1 [BB][DIN] @0 (8 MB); m8T ±1 [DOUT][DIN] @8MB (16 MB).
//
// R7 post-mortem: 60.6us, MfmaUtil 22% -> barrier-latency-bound: each BK=64
// chunk = ~150cyc compute vs ~300cyc exposed vmcnt(0) drain at the barrier
// (64 barriers). Conflicts 4.19M = 4cyc/ds_read (4-way quad floor).
// R8: BK=128 (32 barriers, 2x compute/barrier), XCD-aware 8x8-patch block
// swizzle (FETCH 41->~28MB), slot = g ^ (row&7) over 8 k-groups.
// ---------------------------------------------------------------------------

using v4i  = __attribute__((ext_vector_type(4)))  int;
using v16i = __attribute__((ext_vector_type(16))) int;

__device__ __forceinline__ void async_load16(const void* g, void* l) {
    __builtin_amdgcn_global_load_lds(
        (const __attribute__((address_space(1))) unsigned int*)g,
        (__attribute__((address_space(3))) unsigned int*)l,
        16, 0, 0);
}

// bytes {0,1} -> {+1, -1(0xFF)}; no cross-byte carries.
__device__ __forceinline__ unsigned int to_pm1(unsigned int c) {
    return c + ((c ^ 0x01010101u) * 255u);
}

// Fused packing (verified R7).
// blocks [0,BB): x int32 {0,1} row -> x8 ±1 bytes (same layout).
// blocks [BB, BB+4096): 64x64 transpose tile of masks -> m8T ±1 bytes.
__global__ void pack_all(const int* __restrict__ x,
                         const void* __restrict__ mraw,
                         char* __restrict__ x8,
                         char* __restrict__ m8T) {
    const int tid = threadIdx.x;
    if (blockIdx.x < BB) {
        const int row = blockIdx.x;
        const int4* src = (const int4*)(x + (size_t)row * DIN);
        unsigned int* dst = (unsigned int*)(x8 + (size_t)row * DIN);
        #pragma unroll
        for (int q = 0; q < 4; ++q) {
            int4 v = src[q * 256 + tid];           // coalesced 16B/lane
            unsigned int t = (unsigned int)(v.x & 1) |
                             ((unsigned int)(v.y & 1) << 8) |
                             ((unsigned int)(v.z & 1) << 16) |
                             ((unsigned int)(v.w & 1) << 24);
            dst[q * 256 + tid] = to_pm1(t);        // coalesced 4B/lane
        }
    } else {
        const int bw = blockIdx.x - BB;            // 0..4095
        const int k0 = (bw & 63) * 64;
        const int n0 = (bw >> 6) * 64;

        // inline dtype detect (u8-bool vs int32): wave-reduce 1 KB prefix.
        const unsigned char* mb = (const unsigned char*)mraw;
        int myv = (mb[tid] != 0) + (mb[tid + 256] != 0) +
                  (mb[tid + 512] != 0) + (mb[tid + 768] != 0);
        #pragma unroll
        for (int d = 32; d; d >>= 1) myv += __shfl_xor(myv, d);
        const bool isU8 = (myv > 64);   // u8 ~128/wave, int32 ~32/wave

        // 4x4 byte micro-tile per thread: rows k0+k4..+3, cols n0+n4..+3
        const int n4 = (tid & 15) * 4;
        const int k4 = (tid >> 4) * 4;
        unsigned int a[4];
        if (isU8) {
            #pragma unroll
            for (int r = 0; r < 4; ++r)
                a[r] = *(const unsigned int*)(mb + (size_t)(k0 + k4 + r) * DOUT + n0 + n4);
        } else {
            const int4* m32 = (const int4*)mraw;
            #pragma unroll
            for (int r = 0; r < 4; ++r) {
                int4 v = m32[((size_t)(k0 + k4 + r) * DOUT + n0 + n4) >> 2];
                a[r] = (unsigned int)(v.x & 1) |
                       ((unsigned int)(v.y & 1) << 8) |
                       ((unsigned int)(v.z & 1) << 16) |
                       ((unsigned int)(v.w & 1) << 24);
            }
        }
        // 4x4 byte transpose via v_perm (sel 0-3 = src1/lo, 4-7 = src0/hi)
        unsigned int x0 = __builtin_amdgcn_perm(a[1], a[0], 0x05010400u);
        unsigned int x1 = __builtin_amdgcn_perm(a[3], a[2], 0x05010400u);
        unsigned int x2 = __builtin_amdgcn_perm(a[1], a[0], 0x07030602u);
        unsigned int x3 = __builtin_amdgcn_perm(a[3], a[2], 0x07030602u);
        unsigned int c0 = __builtin_amdgcn_perm(x1, x0, 0x05040100u);
        unsigned int c1 = __builtin_amdgcn_perm(x1, x0, 0x07060302u);
        unsigned int c2 = __builtin_amdgcn_perm(x3, x2, 0x05040100u);
        unsigned int c3 = __builtin_amdgcn_perm(x3, x2, 0x07060302u);
        *(unsigned int*)(m8T + (size_t)(n0 + n4 + 0) * DIN + k0 + k4) = to_pm1(c0);
        *(unsigned int*)(m8T + (size_t)(n0 + n4 + 1) * DIN + k0 + k4) = to_pm1(c1);
        *(unsigned int*)(m8T + (size_t)(n0 + n4 + 2) * DIN + k0 + k4) = to_pm1(c2);
        *(unsigned int*)(m8T + (size_t)(n0 + n4 + 3) * DIN + k0 + k4) = to_pm1(c3);
    }
}

// i8 MFMA GEMM: 128(m)x128(n) block tile, 4 waves as 2x2 of 64x64 wave
// tiles (2x2 of v_mfma_i32_32x32x32_i8 each). BK=128 chunks (32 barriers),
// double-buffered LDS (64 KB), async global->LDS staging.
// LDS layout: [row][slot], slot = kgroup ^ (row&7), 8 kgroups x 16 B.
__global__ __launch_bounds__(256)
void bgemm(const char* __restrict__ x8,
           const char* __restrict__ m8T,
           const int* __restrict__ thr,
           int* __restrict__ out) {
    // XCD-aware swizzle: flat%8 = XCD (round-robin heuristic); each XCD gets
    // a compact 8m x 8n patch -> per-XCD L2 set ~8 MB instead of ~16.
    const int flat = blockIdx.y * 32 + blockIdx.x;
    const int xcd  = flat & 7;
    const int idx  = flat >> 3;                    // 0..63
    const int bm   = (xcd & 1) * 8 + (idx & 7);    // 0..15
    const int bn   = (xcd >> 1) * 8 + (idx >> 3);  // 0..31
    const int b0   = bm * 128;                     // m
    const int o0   = bn * 128;                     // n

    const int tid  = threadIdx.x;
    const int lane = tid & 63;
    const int wv   = tid >> 6;
    const int wm   = (wv & 1) * 64;      // wave tile m origin
    const int wn   = (wv >> 1) * 64;     // wave tile n origin
    const int l31  = lane & 31;
    const int lh   = lane >> 5;
    const int rsw  = l31 & 7;            // row&7 term for frag reads

    __shared__ __align__(16) char lA[2][128 * 128];
    __shared__ __align__(16) char lB[2][128 * 128];

    // stage chunk c -> buf. Per instr: 8 rows x 128 B contiguous LDS.
    // lane: row = r0 + l/8, slot s = l&7, global kgroup g = s ^ (row&7).
    auto stage = [&](int c, int buf) {
        const int k0  = c * 128;
        const int r8  = lane >> 3;
        const int s   = lane & 7;
        #pragma unroll
        for (int h = 0; h < 4; ++h) {
            const int r0  = wv * 32 + h * 8;
            const int row = r0 + r8;
            const int g   = s ^ (row & 7);
            async_load16(x8 + (size_t)(b0 + row) * DIN + k0 + g * 16,
                         &lA[buf][r0 * 128 + lane * 16]);
            async_load16(m8T + (size_t)(o0 + row) * DIN + k0 + g * 16,
                         &lB[buf][r0 * 128 + lane * 16]);
        }
    };

    v16i acc[2][2];
    #pragma unroll
    for (int t = 0; t < 2; ++t)
        #pragma unroll
        for (int u = 0; u < 2; ++u)
            acc[t][u] = (v16i)(0);

    stage(0, 0);
    __syncthreads();

    for (int c = 0; c < 32; ++c) {
        const int buf = c & 1;
        if (c < 31) stage(c + 1, buf ^ 1);   // async, overlaps compute

        #pragma unroll
        for (int ks = 0; ks < 4; ++ks) {
            // slot of global kgroup (ks*2+lh) for this lane's rows
            // (rows wm/wn + t*32 + l31: row&7 == l31&7 == rsw)
            const int slot = ((ks * 2 + lh) ^ rsw) * 16;
            v4i aF[2], bF[2];
            #pragma unroll
            for (int t = 0; t < 2; ++t) {
                aF[t] = *(const v4i*)&lA[buf][(wm + t * 32 + l31) * 128 + slot];
                bF[t] = *(const v4i*)&lB[buf][(wn + t * 32 + l31) * 128 + slot];
            }
            acc[0][0] = __builtin_amdgcn_mfma_i32_32x32x32_i8(aF[0], bF[0], acc[0][0], 0, 0, 0);
            acc[0][1] = __builtin_amdgcn_mfma_i32_32x32x32_i8(aF[0], bF[1], acc[0][1], 0, 0, 0);
            acc[1][0] = __builtin_amdgcn_mfma_i32_32x32x32_i8(aF[1], bF[0], acc[1][0], 0, 0, 0);
            acc[1][1] = __builtin_amdgcn_mfma_i32_32x32x32_i8(aF[1], bF[1], acc[1][1], 0, 0, 0);
        }
        __syncthreads();   // drains chunk+1 loads; releases buf
    }

    // epilogue: out = (dot± > 2*thr - 4096).
    // C/D layout (verified R7): col = lane&31; row = (reg&3)+8*(reg>>2)+4*(lane>>5).
    #pragma unroll
    for (int u = 0; u < 2; ++u) {
        const int o   = o0 + wn + u * 32 + l31;
        const int lim = 2 * thr[o] - DIN;
        #pragma unroll
        for (int t = 0; t < 2; ++t) {
            #pragma unroll
            for (int r = 0; r < 16; ++r) {
                const int rowl = (r & 3) + 8 * (r >> 2) + 4 * lh;
                const int b    = b0 + wm + t * 32 + rowl;
                out[(size_t)b * DOUT + o] = (acc[t][u][r] > lim) ? 1 : 0;
            }
        }
    }
}

extern "C" void kernel_launch(void* const* d_in, const int* in_sizes, int n_in,
                              void* d_out, int out_size, void* d_ws, size_t ws_size,
                              hipStream_t stream) {
    const int* x          = (const int*)d_in[0];
    const void* masks     = d_in[1];           // bool: u8 or int32 (detected inline)
    const int* thresholds = (const int*)d_in[2];
    int* out              = (int*)d_out;

    char* x8  = (char*)d_ws;                          // 8 MB
    char* m8T = (char*)d_ws + ((size_t)8 << 20);      // 16 MB

    pack_all<<<BB + 4096, 256, 0, stream>>>(x, masks, x8, m8T);
    bgemm<<<dim3(32, 16), 256, 0, stream>>>(x8, m8T, thresholds, out);
}